// Round 9
// baseline (665.111 us; speedup 1.0000x reference)
//
#include <hip/hip_runtime.h>
#include <math.h>
#include <limits.h>

#define EPSB 1e-5f
#define R2C  0.09f

// ---- workspace offsets (floats). Total ~4.44M floats = ~17.8 MB ----
#define OFF_MASKF 0          // N*16
#define OFF_KERNF 1600000    // N*16  (dead after k_prep -> merge partials live here)
#define OFF_STATS 3200000    // (unused)
#define OFF_VT    3202048    // 128*352
#define OFF_FEATW 3247104    // 128*36
#define OFF_MZ1   3251712    // tower partials (TPA/TPB) live here
#define OFF_MZ2   3841536    // (unused)
#define OFF_INT   4431360    // 256 ints (topk 128 | cand_batch 128)

// ============================ fused tower layer ===========================
// blockIdx.y = tower (0: mask, 1: kernel).
// BN stats: producer blocks write per-block partial (sum,sumsq) rows
// NON-ATOMICALLY to tp_out[(tw*gridDim.x + blk)*64 + {0..63}]; consumer
// reduces at head with 4 independent fp64 accumulators (loads pipeline).
// Stats computed from the As stage-out tile via LDS column sums.
template <int COLS>
__global__ __launch_bounds__(256)
void k_tower2(const float* __restrict__ X0, const float* __restrict__ X1,
              const float* __restrict__ W0, const float* __restrict__ W1,
              const float* __restrict__ b0, const float* __restrict__ b1,
              float* __restrict__ Y0, float* __restrict__ Y1,
              const double* __restrict__ tp_in, double* __restrict__ tp_out,
              int N) {
    __shared__ float As[256 * 33];
    __shared__ float mrs[64];
    __shared__ float redS[256];
    __shared__ float redQ[256];
    __shared__ double redd[256];
    int tid = threadIdx.x;
    int tw = blockIdx.y;
    const float* X = tw ? X1 : X0;
    const float* W = tw ? W1 : W0;
    const float* bias = tw ? b1 : b0;
    float* Y = tw ? Y1 : Y0;

    bool nrm = (tp_in != nullptr);
    if (nrm) {
        int col = tid & 63, part = tid >> 6;
        const double* src = tp_in + (size_t)tw * gridDim.x * 64 + col;
        int nb = (int)gridDim.x;
        double a0 = 0.0, a1 = 0.0, a2 = 0.0, a3 = 0.0;
        int b = part;
        for (; b + 12 < nb; b += 16) {
            a0 += src[(size_t)b * 64];
            a1 += src[(size_t)(b + 4) * 64];
            a2 += src[(size_t)(b + 8) * 64];
            a3 += src[(size_t)(b + 12) * 64];
        }
        for (; b < nb; b += 4) a0 += src[(size_t)b * 64];
        redd[part * 64 + col] = (a0 + a1) + (a2 + a3);
        __syncthreads();
        if (tid < 32) {
            double S = redd[tid] + redd[64 + tid] + redd[128 + tid] + redd[192 + tid];
            double Q = redd[32 + tid] + redd[96 + tid] + redd[160 + tid] + redd[224 + tid];
            double m = S / (double)N;
            double v = Q / (double)N - m * m;
            mrs[tid] = (float)m; mrs[32 + tid] = (float)rsqrt(v + (double)EPSB);
        }
    }
    __syncthreads();
    int rbase = blockIdx.x * 256;
    int rmax = N - rbase; if (rmax > 256) rmax = 256;
    const float4* Xv = (const float4*)(X + (size_t)rbase * 32);
    for (int f = tid; f < 2048; f += 256) {
        int r = f >> 3, c0 = (f & 7) * 4;
        float4 v = make_float4(0.f, 0.f, 0.f, 0.f);
        if (r < rmax) v = Xv[f];
        float e[4] = {v.x, v.y, v.z, v.w};
        float* dst = &As[r * 33 + c0];
#pragma unroll
        for (int u = 0; u < 4; u++) {
            float t = e[u];
            if (nrm) t = fmaxf((t - mrs[c0 + u]) * mrs[32 + c0 + u], 0.f);
            dst[u] = t;
        }
    }
    __syncthreads();
    float acc[COLS];
#pragma unroll
    for (int j = 0; j < COLS; j++) acc[j] = 0.f;
    if (bias) {
#pragma unroll
        for (int j = 0; j < COLS; j++) acc[j] = bias[j];
    }
#pragma unroll 4
    for (int k = 0; k < 32; k++) {
        float a = As[tid * 33 + k];
        const float* wr = W + k * COLS;   // wave-uniform -> scalar loads
#pragma unroll
        for (int j = 0; j < COLS; j++) acc[j] = fmaf(a, wr[j], acc[j]);
    }
    __syncthreads();
#pragma unroll
    for (int j = 0; j < COLS; j++) As[tid * 33 + j] = acc[j];
    __syncthreads();
    constexpr int C4 = COLS / 4;
    for (int f = tid; f < 256 * C4; f += 256) {
        int r = f / C4, c0 = (f % C4) * 4;
        if (r < rmax) {
            const float* sp = &As[r * 33 + c0];
            float4 o = {sp[0], sp[1], sp[2], sp[3]};
            *(float4*)(Y + (size_t)(rbase + r) * COLS + c0) = o;
        }
    }
    if constexpr (COLS == 32) {
        if (tp_out) {
            int j = tid & 31, g = tid >> 5;     // 8 groups x 32 rows each
            float s = 0.f, q = 0.f;
#pragma unroll
            for (int i = 0; i < 32; i++) {
                float v = As[(g * 32 + i) * 33 + j];   // bank (i+j)%32: conflict-free
                s += v; q = fmaf(v, v, q);
            }
            redS[tid] = s; redQ[tid] = q;
            __syncthreads();
            if (tid < 64) {
                int jj = tid & 31;
                const float* rp = (tid < 32) ? redS : redQ;
                double acc2 = 0.0;
#pragma unroll
                for (int g2 = 0; g2 < 8; g2++) acc2 += (double)rp[g2 * 32 + jj];
                tp_out[((size_t)tw * gridDim.x + blockIdx.x) * 64 + tid] = acc2;
            }
        }
    }
}

// ================================= NMS ====================================
#define NBINS 2048
#define NMC   1024
#define NCAP  1088
#define SLOTS 17
__global__ __launch_bounds__(1024)
void k_nms(const float* __restrict__ heat, const float* __restrict__ coords,
           const int* __restrict__ bidx, int N, int* __restrict__ topk) {
    __shared__ int   hist[NBINS];
    __shared__ float ch[NCAP], cxs[NCAP], cys[NCAP], czs[NCAP];
    __shared__ int   cid[NCAP];
    __shared__ int   sh_s, sh_e, sh_T, sh_cnt;
    __shared__ float sh_val;
    __shared__ float rv[16]; __shared__ int ri[16];
    __shared__ float fbx[32], fby[32], fbz[32];
    int b = blockIdx.x, tid = threadIdx.x;
    if (tid == 0) {
        int lo = 0, hi = N;
        while (lo < hi) { int m = (lo + hi) >> 1; if (bidx[m] < b) lo = m + 1; else hi = m; }
        sh_s = lo;
        lo = 0; hi = N;
        while (lo < hi) { int m = (lo + hi) >> 1; if (bidx[m] < b + 1) lo = m + 1; else hi = m; }
        sh_e = lo;
    }
    __syncthreads();
    int s = sh_s, e = sh_e, nb = e - s;
    if (nb <= 0) {
        if (tid < 32) topk[b * 32 + tid] = 0;
        return;
    }
    for (int i = tid; i < NBINS; i += 1024) hist[i] = 0;
    __syncthreads();
    for (int n = s + tid; n < e; n += 1024) {
        float h = heat[n];
        int bin = (int)(h * (float)NBINS);
        bin = min(max(bin, 0), NBINS - 1);
        atomicAdd(&hist[bin], 1);
    }
    __syncthreads();
    for (int off = 1; off < NBINS; off <<= 1) {
        int v[2];
#pragma unroll
        for (int u = 0; u < 2; u++) {
            int i = tid + u * 1024;
            v[u] = hist[i] + ((i + off < NBINS) ? hist[i + off] : 0);
        }
        __syncthreads();
#pragma unroll
        for (int u = 0; u < 2; u++) hist[tid + u * 1024] = v[u];
        __syncthreads();
    }
    int Meff = min(NMC, nb);
#pragma unroll
    for (int u = 0; u < 2; u++) {
        int i = tid + u * 1024;
        if (hist[i] >= Meff && (i == NBINS - 1 || hist[i + 1] < Meff)) sh_T = i;
    }
    if (tid == 0) sh_cnt = 0;
    __syncthreads();
    int T = sh_T;
    float thr = (float)T * (1.0f / (float)NBINS);
    for (int n = s + tid; n < e; n += 1024) {
        float h = heat[n];
        int bin = (int)(h * (float)NBINS);
        bin = min(max(bin, 0), NBINS - 1);
        if (bin >= T) {
            int p = atomicAdd(&sh_cnt, 1);
            if (p < NCAP) {
                ch[p] = h; cid[p] = n;
                cxs[p] = coords[(size_t)n * 3 + 0];
                cys[p] = coords[(size_t)n * 3 + 1];
                czs[p] = coords[(size_t)n * 3 + 2];
            }
        }
    }
    __syncthreads();
    int C = min(sh_cnt, NCAP);
    bool overflow = (sh_cnt > NCAP);
    if (tid < 64) {
        float hh[SLOTS], xx[SLOTS], yy[SLOTS], zz[SLOTS];
        int ii[SLOTS];
#pragma unroll
        for (int m = 0; m < SLOTS; m++) {
            int i = m * 64 + tid;
            if (i < C) { hh[m] = ch[i]; xx[m] = cxs[i]; yy[m] = cys[i]; zz[m] = czs[i]; ii[m] = cid[i]; }
            else { hh[m] = -INFINITY; xx[m] = 1e30f; yy[m] = 1e30f; zz[m] = 1e30f; ii[m] = INT_MAX; }
        }
        float last = -INFINITY;
        for (int t = 0; t < 32; t++) {
            float bv = -INFINITY, bx = 0.f, by = 0.f, bz = 0.f;
            int bo = INT_MAX;
#pragma unroll
            for (int m = 0; m < SLOTS; m++) {
                bool c = (hh[m] > bv) || (hh[m] == bv && ii[m] < bo);
                if (c) { bv = hh[m]; bo = ii[m]; bx = xx[m]; by = yy[m]; bz = zz[m]; }
            }
#pragma unroll
            for (int off = 32; off > 0; off >>= 1) {
                float ov = __shfl_down(bv, off);
                int   oo = __shfl_down(bo, off);
                float ox = __shfl_down(bx, off);
                float oy = __shfl_down(by, off);
                float oz = __shfl_down(bz, off);
                bool c = (ov > bv) || (ov == bv && oo < bo);
                if (c) { bv = ov; bo = oo; bx = ox; by = oy; bz = oz; }
            }
            bv = __shfl(bv, 0); bo = __shfl(bo, 0);
            bx = __shfl(bx, 0); by = __shfl(by, 0); bz = __shfl(bz, 0);
            if (tid == 0) topk[b * 32 + t] = bo;
            last = bv;
#pragma unroll
            for (int m = 0; m < SLOTS; m++) {
                float dx = xx[m] - bx, dy = yy[m] - by, dz = zz[m] - bz;
                if (dx * dx + dy * dy + dz * dz < R2C) hh[m] = -INFINITY;
            }
        }
        if (tid == 0) sh_val = last;
    }
    __syncthreads();
    bool sound = (!overflow) && (C > 0) && (sh_val >= thr);
    if (!sound) {
        for (int t = 0; t < 32; t++) {
            float bv = -INFINITY; int bo = INT_MAX;
            for (int n = s + tid; n < e; n += 1024) {
                float x = coords[(size_t)n * 3], y = coords[(size_t)n * 3 + 1], z = coords[(size_t)n * 3 + 2];
                bool sup = false;
                for (int u = 0; u < t; u++) {
                    float dx = x - fbx[u], dy = y - fby[u], dz = z - fbz[u];
                    if (dx * dx + dy * dy + dz * dz < R2C) { sup = true; break; }
                }
                if (!sup) {
                    float h = heat[n];
                    if (h > bv || (h == bv && n < bo)) { bv = h; bo = n; }
                }
            }
#pragma unroll
            for (int off = 32; off > 0; off >>= 1) {
                float ov = __shfl_down(bv, off); int oo = __shfl_down(bo, off);
                if (ov > bv || (ov == bv && oo < bo)) { bv = ov; bo = oo; }
            }
            if ((tid & 63) == 0) { int w = tid >> 6; rv[w] = bv; ri[w] = bo; }
            __syncthreads();
            if (tid == 0) {
                bv = rv[0]; bo = ri[0];
                for (int w = 1; w < 16; w++)
                    if (rv[w] > bv || (rv[w] == bv && ri[w] < bo)) { bv = rv[w]; bo = ri[w]; }
                if (bo == INT_MAX) bo = 0;
                topk[b * 32 + t] = bo;
                fbx[t] = coords[(size_t)bo * 3];
                fby[t] = coords[(size_t)bo * 3 + 1];
                fbz[t] = coords[(size_t)bo * 3 + 2];
            }
            __syncthreads();
        }
    }
}

// ============================ instance prep ===============================
__global__ __launch_bounds__(384)
void k_prep(const int* __restrict__ topk, const float* __restrict__ coords,
            const int* __restrict__ bidx, const float* __restrict__ maskf,
            const float* __restrict__ kernf, const float* __restrict__ Wwg,
            const float* __restrict__ bwg, float* __restrict__ Vt,
            float* __restrict__ featw, int* __restrict__ cand_batch) {
    __shared__ float ck[16], cm[16], ctr[3], wrow[337];
    int i = blockIdx.x, tid = threadIdx.x;
    int idx = topk[i];
    if (tid < 16) { ck[tid] = kernf[(size_t)idx * 16 + tid]; cm[tid] = maskf[(size_t)idx * 16 + tid]; }
    else if (tid < 19) ctr[tid - 16] = coords[(size_t)idx * 3 + (tid - 16)];
    else if (tid == 19) cand_batch[i] = bidx[idx];
    __syncthreads();
    for (int c = tid; c < 337; c += 384) {
        float acc = bwg[c];
#pragma unroll
        for (int m = 0; m < 16; m++) acc += ck[m] * Wwg[m * 337 + c];
        wrow[c] = acc;
    }
    __syncthreads();
    for (int t = tid; t < 352; t += 384) {
        float v;
        if (t < 320) {
            int k = t >> 4, j = t & 15;
            if (k < 19) v = wrow[k * 16 + j];
            else {
                v = wrow[304 + j];
#pragma unroll
                for (int p = 0; p < 3; p++) v -= ctr[p] * wrow[(16 + p) * 16 + j];
            }
        } else if (t < 336) v = wrow[320 + (t - 320)];
        else if (t == 336) v = wrow[336];
        else v = 0.f;
        Vt[(size_t)i * 352 + t] = v;
    }
    for (int t = tid; t < 36; t += 384)
        featw[i * 36 + t] = (t < 16) ? ck[t] : (t < 32) ? cm[t - 16] : (t < 35) ? ctr[t - 32] : 0.f;
}

// ============================== mask heads ================================
// Activations live in LDS (als[20][256], each thread reads only its own
// column -> conflict-free). 16 named h-accumulators per instance: per k,
// 1 ds_read_b32 + 4 s_load_dwordx4 feed 16 fma -> VALU nearly pure fma.
#define MASK_PER 16
#define MROW(K) { float a = al[(K) * 256]; \
    float4 w0 = V4[(K)*4], w1 = V4[(K)*4+1], w2 = V4[(K)*4+2], w3 = V4[(K)*4+3]; \
    h0 = fmaf(a, w0.x, h0);  h1 = fmaf(a, w0.y, h1);  h2 = fmaf(a, w0.z, h2);  h3 = fmaf(a, w0.w, h3); \
    h4 = fmaf(a, w1.x, h4);  h5 = fmaf(a, w1.y, h5);  h6 = fmaf(a, w1.z, h6);  h7 = fmaf(a, w1.w, h7); \
    h8 = fmaf(a, w2.x, h8);  h9 = fmaf(a, w2.y, h9);  h10 = fmaf(a, w2.z, h10); h11 = fmaf(a, w2.w, h11); \
    h12 = fmaf(a, w3.x, h12); h13 = fmaf(a, w3.y, h13); h14 = fmaf(a, w3.z, h14); h15 = fmaf(a, w3.w, h15); }
__global__ __launch_bounds__(256)
void k_mask(const float* __restrict__ maskf, const float* __restrict__ coords,
            const float* __restrict__ Vt, float* __restrict__ out,
            int N, int ostride) {
    __shared__ float als[20 * 256];
    int tid = threadIdx.x;
    int n = blockIdx.x * 256 + tid;
    bool valid = (n < N);
    int nc = valid ? n : (N - 1);
    {
        const float4* fr = (const float4*)(maskf + (size_t)nc * 16);
        float4 P = fr[0], Q = fr[1], R = fr[2], S = fr[3];
        als[0*256+tid]=P.x;  als[1*256+tid]=P.y;  als[2*256+tid]=P.z;  als[3*256+tid]=P.w;
        als[4*256+tid]=Q.x;  als[5*256+tid]=Q.y;  als[6*256+tid]=Q.z;  als[7*256+tid]=Q.w;
        als[8*256+tid]=R.x;  als[9*256+tid]=R.y;  als[10*256+tid]=R.z; als[11*256+tid]=R.w;
        als[12*256+tid]=S.x; als[13*256+tid]=S.y; als[14*256+tid]=S.z; als[15*256+tid]=S.w;
        als[16*256+tid]=coords[(size_t)nc*3];
        als[17*256+tid]=coords[(size_t)nc*3+1];
        als[18*256+tid]=coords[(size_t)nc*3+2];
        als[19*256+tid]=1.f;
    }
    const float* al = als + tid;
    int ibase = blockIdx.y * MASK_PER;
    const float4* __restrict__ V4 = (const float4*)(Vt + (size_t)ibase * 352);  // block-uniform
    float* op = out + (size_t)ibase * ostride + n;
    for (int ii = 0; ii < MASK_PER; ii++) {
        float h0=0.f,h1=0.f,h2=0.f,h3=0.f,h4=0.f,h5=0.f,h6=0.f,h7=0.f;
        float h8=0.f,h9=0.f,h10=0.f,h11=0.f,h12=0.f,h13=0.f,h14=0.f,h15=0.f;
        MROW(0)  MROW(1)  MROW(2)  MROW(3)  MROW(4)
        MROW(5)  MROW(6)  MROW(7)  MROW(8)  MROW(9)
        MROW(10) MROW(11) MROW(12) MROW(13) MROW(14)
        MROW(15) MROW(16) MROW(17) MROW(18) MROW(19)
        float4 u0 = V4[80], u1 = V4[81], u2 = V4[82], u3 = V4[83];
        float acc = V4[84].x;               // V[336] = b2
        acc = fmaf(fmaxf(h0, 0.f),  u0.x, acc);
        acc = fmaf(fmaxf(h1, 0.f),  u0.y, acc);
        acc = fmaf(fmaxf(h2, 0.f),  u0.z, acc);
        acc = fmaf(fmaxf(h3, 0.f),  u0.w, acc);
        acc = fmaf(fmaxf(h4, 0.f),  u1.x, acc);
        acc = fmaf(fmaxf(h5, 0.f),  u1.y, acc);
        acc = fmaf(fmaxf(h6, 0.f),  u1.z, acc);
        acc = fmaf(fmaxf(h7, 0.f),  u1.w, acc);
        acc = fmaf(fmaxf(h8, 0.f),  u2.x, acc);
        acc = fmaf(fmaxf(h9, 0.f),  u2.y, acc);
        acc = fmaf(fmaxf(h10, 0.f), u2.z, acc);
        acc = fmaf(fmaxf(h11, 0.f), u2.w, acc);
        acc = fmaf(fmaxf(h12, 0.f), u3.x, acc);
        acc = fmaf(fmaxf(h13, 0.f), u3.y, acc);
        acc = fmaf(fmaxf(h14, 0.f), u3.z, acc);
        acc = fmaf(fmaxf(h15, 0.f), u3.w, acc);
        if (valid) *op = 1.f / (1.f + __expf(-acc));
        V4 += 88;                            // 352/4
        op += ostride;
    }
}

// ============================== merge tower ===============================
// Split chain (stream boundaries = free device-wide visibility, no barrier,
// no atomics). Fixes vs rounds 0-6: (1) Z is COLUMN-MAJOR Z[j*16384+id] so
// every store/load instruction is perfectly coalesced (old row-major
// stride-36 scattered 64 lanes over ~64 cache lines -> 190us kernels);
// (2) normalize fused on the fly -- no x[] array (rule #20 scratch risk);
// z[35] statically indexed, fully unrolled. Partial-row stats as before.
#define MROWS 16384
__global__ __launch_bounds__(256)
void k_merge1(const float* __restrict__ featw, const float* __restrict__ Wg,
              float* __restrict__ Z, double* __restrict__ pout) {
    __shared__ float F[128 * 36];
    __shared__ double redm[280];
    int tid = threadIdx.x;
    for (int t = tid; t < 128 * 36; t += 256) F[t] = featw[t];
    __syncthreads();
    int id = blockIdx.x * 256 + tid;
    int a = id >> 7, b = id & 127;
    float z[35];
#pragma unroll
    for (int j = 0; j < 35; j++) z[j] = 0.f;
#pragma unroll
    for (int k = 0; k < 35; k++) {
        float dk = fmaxf(fabsf(F[a * 36 + k] - F[b * 36 + k]), 1e-6f);
        const float* wr = Wg + k * 35;        // wave-uniform -> s_loads
#pragma unroll
        for (int j = 0; j < 35; j++) z[j] = fmaf(dk, wr[j], z[j]);
    }
    int wv = tid >> 6;
#pragma unroll
    for (int j = 0; j < 35; j++) {
        float s = z[j], q = z[j] * z[j];
#pragma unroll
        for (int off = 32; off > 0; off >>= 1) { s += __shfl_down(s, off); q += __shfl_down(q, off); }
        if ((tid & 63) == 0) { redm[wv * 70 + j] = (double)s; redm[wv * 70 + 35 + j] = (double)q; }
    }
    __syncthreads();
    if (tid < 70) {
        double t = redm[tid] + redm[70 + tid] + redm[140 + tid] + redm[210 + tid];
        pout[(size_t)blockIdx.x * 70 + tid] = t;
    }
#pragma unroll
    for (int j = 0; j < 35; j++) Z[(size_t)j * MROWS + id] = z[j];   // coalesced
}

__global__ __launch_bounds__(256)
void k_merge_mid(const float* __restrict__ Zin, const float* __restrict__ Wg,
                 float* __restrict__ Zout, const double* __restrict__ pin,
                 double* __restrict__ pout) {
    __shared__ float nrm[70];
    __shared__ double sred[70];
    __shared__ double redm[280];
    int tid = threadIdx.x;
    if (tid < 70) {
        double a0 = 0.0, a1 = 0.0, a2 = 0.0, a3 = 0.0;
#pragma unroll
        for (int b = 0; b < 64; b += 4) {
            a0 += pin[(size_t)b * 70 + tid];
            a1 += pin[(size_t)(b + 1) * 70 + tid];
            a2 += pin[(size_t)(b + 2) * 70 + tid];
            a3 += pin[(size_t)(b + 3) * 70 + tid];
        }
        sred[tid] = (a0 + a1) + (a2 + a3);
    }
    __syncthreads();
    if (tid < 35) {
        double m = sred[tid] * (1.0 / 16384.0);
        double v = sred[35 + tid] * (1.0 / 16384.0) - m * m;
        nrm[tid] = (float)m; nrm[35 + tid] = (float)rsqrt(v + (double)EPSB);
    }
    __syncthreads();
    int id = blockIdx.x * 256 + tid;
    float z[35];
#pragma unroll
    for (int j = 0; j < 35; j++) z[j] = 0.f;
#pragma unroll
    for (int k = 0; k < 35; k++) {
        float zk = Zin[(size_t)k * MROWS + id];            // coalesced
        float dk = fmaxf((zk - nrm[k]) * nrm[35 + k], 0.f); // fused normalize
        const float* wr = Wg + k * 35;
#pragma unroll
        for (int j = 0; j < 35; j++) z[j] = fmaf(dk, wr[j], z[j]);
    }
    int wv = tid >> 6;
#pragma unroll
    for (int j = 0; j < 35; j++) {
        float s = z[j], q = z[j] * z[j];
#pragma unroll
        for (int off = 32; off > 0; off >>= 1) { s += __shfl_down(s, off); q += __shfl_down(q, off); }
        if ((tid & 63) == 0) { redm[wv * 70 + j] = (double)s; redm[wv * 70 + 35 + j] = (double)q; }
    }
    __syncthreads();
    if (tid < 70) {
        double t = redm[tid] + redm[70 + tid] + redm[140 + tid] + redm[210 + tid];
        pout[(size_t)blockIdx.x * 70 + tid] = t;
    }
#pragma unroll
    for (int j = 0; j < 35; j++) Zout[(size_t)j * MROWS + id] = z[j];
}

__global__ __launch_bounds__(256)
void k_merge_out(const float* __restrict__ Zin, const float* __restrict__ Wout,
                 const float* __restrict__ bout, const double* __restrict__ pin,
                 const int* __restrict__ cand_batch, float* __restrict__ out,
                 int N, int ostride) {
    __shared__ float nrm[70];
    __shared__ double sred[70];
    __shared__ int cb[128];
    int tid = threadIdx.x;
    if (tid < 70) {
        double a0 = 0.0, a1 = 0.0, a2 = 0.0, a3 = 0.0;
#pragma unroll
        for (int b = 0; b < 64; b += 4) {
            a0 += pin[(size_t)b * 70 + tid];
            a1 += pin[(size_t)(b + 1) * 70 + tid];
            a2 += pin[(size_t)(b + 2) * 70 + tid];
            a3 += pin[(size_t)(b + 3) * 70 + tid];
        }
        sred[tid] = (a0 + a1) + (a2 + a3);
    }
    if (tid >= 128 && tid < 256) cb[tid - 128] = cand_batch[tid - 128];
    __syncthreads();
    if (tid < 35) {
        double m = sred[tid] * (1.0 / 16384.0);
        double v = sred[35 + tid] * (1.0 / 16384.0) - m * m;
        nrm[tid] = (float)m; nrm[35 + tid] = (float)rsqrt(v + (double)EPSB);
    }
    __syncthreads();
    int id = blockIdx.x * 256 + tid;
    int a = id >> 7, b = id & 127;
    float s = bout[0];
#pragma unroll
    for (int k = 0; k < 35; k++) {
        float zk = Zin[(size_t)k * MROWS + id];            // coalesced
        s = fmaf(fmaxf((zk - nrm[k]) * nrm[35 + k], 0.f), Wout[k], s);
    }
    float v = 1.f / (1.f + __expf(-s));
    if (cb[a] != cb[b]) v = 0.f;
    out[(size_t)a * ostride + N + b] = v;
}

// =============================== launcher =================================
extern "C" void kernel_launch(void* const* d_in, const int* in_sizes, int n_in,
                              void* d_out, int out_size, void* d_ws, size_t ws_size,
                              hipStream_t stream) {
    const float* of     = (const float*)d_in[0];
    const float* coords = (const float*)d_in[1];
    const float* heat   = (const float*)d_in[2];
    const int*   bidx   = (const int*)d_in[3];
    const float* Wm     = (const float*)d_in[4];
    const float* Wm_out = (const float*)d_in[5];
    const float* bm_out = (const float*)d_in[6];
    const float* Wk     = (const float*)d_in[7];
    const float* Wk_out = (const float*)d_in[8];
    const float* bk_out = (const float*)d_in[9];
    const float* Wg     = (const float*)d_in[10];
    const float* Wg_out = (const float*)d_in[11];
    const float* bg_out = (const float*)d_in[12];
    const float* Wwg    = (const float*)d_in[13];
    const float* bwg    = (const float*)d_in[14];
    float* out = (float*)d_out;
    float* ws  = (float*)d_ws;

    int N = in_sizes[0] / 32;          // 100000
    int ostride = N + 128;             // 100128

    float*  maskf = ws + OFF_MASKF;
    float*  kernf = ws + OFF_KERNF;
    float*  Vt    = ws + OFF_VT;
    float*  featw = ws + OFF_FEATW;
    int*    topk  = (int*)(ws + OFF_INT);
    int*    cand_batch = topk + 128;

    // tower BN partials ping-pong in mz1 region:
    double* TPA = (double*)(ws + OFF_MZ1);
    double* TPB = (double*)(ws + OFF_MZ1 + 131072);
    // merge BN partials in kernf region (dead after k_prep):
    double* P1 = (double*)(ws + OFF_KERNF);
    double* P2 = (double*)(ws + OFF_KERNF + 16384);
    double* P3 = (double*)(ws + OFF_KERNF + 32768);

    // tower ping-pong buffers live inside d_out (dead after towers);
    // merge Z ping-pong reuses d_out scratch too (merge runs BEFORE k_mask,
    // which then overwrites columns 0..N; merge output cols N..N+128 survive).
    float* bufAm = out;
    float* bufBm = out + (size_t)N * 32;
    float* bufAk = out + (size_t)N * 64;
    float* bufBk = out + (size_t)N * 96;
    float* Za    = out + (size_t)N * 64;   // 573440 floats < N*32
    float* Zb    = out + (size_t)N * 96;

    dim3 tg2((N + 255) / 256, 2);

    k_nms<<<4, 1024, 0, stream>>>(heat, coords, bidx, N, topk);
    k_tower2<32><<<tg2, 256, 0, stream>>>(of,    of,    Wm,        Wk,        nullptr, nullptr, bufAm, bufAk, nullptr, TPA,     N);
    k_tower2<32><<<tg2, 256, 0, stream>>>(bufAm, bufAk, Wm + 1024, Wk + 1024, nullptr, nullptr, bufBm, bufBk, TPA,     TPB,     N);
    k_tower2<32><<<tg2, 256, 0, stream>>>(bufBm, bufBk, Wm + 2048, Wk + 2048, nullptr, nullptr, bufAm, bufAk, TPB,     TPA,     N);
    k_tower2<16><<<tg2, 256, 0, stream>>>(bufAm, bufAk, Wm_out,    Wk_out,    bm_out,  bk_out,  maskf, kernf, TPA,     nullptr, N);

    k_prep<<<128, 384, 0, stream>>>(topk, coords, bidx, maskf, kernf, Wwg, bwg,
                                    Vt, featw, cand_batch);

    // merge chain first (Z scratch in d_out), then mask overwrites cols 0..N
    k_merge1<<<64, 256, 0, stream>>>(featw, Wg, Za, P1);
    k_merge_mid<<<64, 256, 0, stream>>>(Za, Wg + 1225, Zb, P1, P2);
    k_merge_mid<<<64, 256, 0, stream>>>(Zb, Wg + 2450, Za, P2, P3);
    k_merge_out<<<64, 256, 0, stream>>>(Za, Wg_out, bg_out, P3, cand_batch,
                                        out, N, ostride);

    k_mask<<<dim3((N + 255) / 256, 8), 256, 0, stream>>>(maskf, coords, Vt, out, N, ostride);
}

// Round 10
// 660.919 us; speedup vs baseline: 1.0063x; 1.0063x over previous
//
#include <hip/hip_runtime.h>
#include <math.h>
#include <limits.h>

#define EPSB 1e-5f
#define R2C  0.09f

// ---- workspace offsets (floats). Total ~4.44M floats = ~17.8 MB ----
#define OFF_MASKF 0          // N*16
#define OFF_KERNF 1600000    // N*16  (dead after k_prep -> merge partials live here)
#define OFF_STATS 3200000    // (unused)
#define OFF_VT    3202048    // 128*352
#define OFF_FEATW 3247104    // 128*36
#define OFF_MZ1   3251712    // tower partials (TPA/TPB) live here
#define OFF_MZ2   3841536    // (unused)
#define OFF_INT   4431360    // 256 ints (topk 128 | cand_batch 128)

// ============================ fused tower layer ===========================
// blockIdx.y = tower (0: mask, 1: kernel).
// BN stats: producer blocks write per-block partial (sum,sumsq) rows
// NON-ATOMICALLY to tp_out[(tw*gridDim.x + blk)*64 + {0..63}]; consumer
// reduces at head with 4 independent fp64 accumulators (loads pipeline).
// Stats computed from the As stage-out tile via LDS column sums.
template <int COLS>
__global__ __launch_bounds__(256)
void k_tower2(const float* __restrict__ X0, const float* __restrict__ X1,
              const float* __restrict__ W0, const float* __restrict__ W1,
              const float* __restrict__ b0, const float* __restrict__ b1,
              float* __restrict__ Y0, float* __restrict__ Y1,
              const double* __restrict__ tp_in, double* __restrict__ tp_out,
              int N) {
    __shared__ float As[256 * 33];
    __shared__ float mrs[64];
    __shared__ float redS[256];
    __shared__ float redQ[256];
    __shared__ double redd[256];
    int tid = threadIdx.x;
    int tw = blockIdx.y;
    const float* X = tw ? X1 : X0;
    const float* W = tw ? W1 : W0;
    const float* bias = tw ? b1 : b0;
    float* Y = tw ? Y1 : Y0;

    bool nrm = (tp_in != nullptr);
    if (nrm) {
        int col = tid & 63, part = tid >> 6;
        const double* src = tp_in + (size_t)tw * gridDim.x * 64 + col;
        int nb = (int)gridDim.x;
        double a0 = 0.0, a1 = 0.0, a2 = 0.0, a3 = 0.0;
        int b = part;
        for (; b + 12 < nb; b += 16) {
            a0 += src[(size_t)b * 64];
            a1 += src[(size_t)(b + 4) * 64];
            a2 += src[(size_t)(b + 8) * 64];
            a3 += src[(size_t)(b + 12) * 64];
        }
        for (; b < nb; b += 4) a0 += src[(size_t)b * 64];
        redd[part * 64 + col] = (a0 + a1) + (a2 + a3);
        __syncthreads();
        if (tid < 32) {
            double S = redd[tid] + redd[64 + tid] + redd[128 + tid] + redd[192 + tid];
            double Q = redd[32 + tid] + redd[96 + tid] + redd[160 + tid] + redd[224 + tid];
            double m = S / (double)N;
            double v = Q / (double)N - m * m;
            mrs[tid] = (float)m; mrs[32 + tid] = (float)rsqrt(v + (double)EPSB);
        }
    }
    __syncthreads();
    int rbase = blockIdx.x * 256;
    int rmax = N - rbase; if (rmax > 256) rmax = 256;
    const float4* Xv = (const float4*)(X + (size_t)rbase * 32);
    for (int f = tid; f < 2048; f += 256) {
        int r = f >> 3, c0 = (f & 7) * 4;
        float4 v = make_float4(0.f, 0.f, 0.f, 0.f);
        if (r < rmax) v = Xv[f];
        float e[4] = {v.x, v.y, v.z, v.w};
        float* dst = &As[r * 33 + c0];
#pragma unroll
        for (int u = 0; u < 4; u++) {
            float t = e[u];
            if (nrm) t = fmaxf((t - mrs[c0 + u]) * mrs[32 + c0 + u], 0.f);
            dst[u] = t;
        }
    }
    __syncthreads();
    float acc[COLS];
#pragma unroll
    for (int j = 0; j < COLS; j++) acc[j] = 0.f;
    if (bias) {
#pragma unroll
        for (int j = 0; j < COLS; j++) acc[j] = bias[j];
    }
#pragma unroll 4
    for (int k = 0; k < 32; k++) {
        float a = As[tid * 33 + k];
        const float* wr = W + k * COLS;   // wave-uniform -> scalar loads
#pragma unroll
        for (int j = 0; j < COLS; j++) acc[j] = fmaf(a, wr[j], acc[j]);
    }
    __syncthreads();
#pragma unroll
    for (int j = 0; j < COLS; j++) As[tid * 33 + j] = acc[j];
    __syncthreads();
    constexpr int C4 = COLS / 4;
    for (int f = tid; f < 256 * C4; f += 256) {
        int r = f / C4, c0 = (f % C4) * 4;
        if (r < rmax) {
            const float* sp = &As[r * 33 + c0];
            float4 o = {sp[0], sp[1], sp[2], sp[3]};
            *(float4*)(Y + (size_t)(rbase + r) * COLS + c0) = o;
        }
    }
    if constexpr (COLS == 32) {
        if (tp_out) {
            int j = tid & 31, g = tid >> 5;     // 8 groups x 32 rows each
            float s = 0.f, q = 0.f;
#pragma unroll
            for (int i = 0; i < 32; i++) {
                float v = As[(g * 32 + i) * 33 + j];   // bank (i+j)%32: conflict-free
                s += v; q = fmaf(v, v, q);
            }
            redS[tid] = s; redQ[tid] = q;
            __syncthreads();
            if (tid < 64) {
                int jj = tid & 31;
                const float* rp = (tid < 32) ? redS : redQ;
                double acc2 = 0.0;
#pragma unroll
                for (int g2 = 0; g2 < 8; g2++) acc2 += (double)rp[g2 * 32 + jj];
                tp_out[((size_t)tw * gridDim.x + blockIdx.x) * 64 + tid] = acc2;
            }
        }
    }
}

// ================================= NMS ====================================
#define NBINS 2048
#define NMC   1024
#define NCAP  1088
#define SLOTS 17
__global__ __launch_bounds__(1024)
void k_nms(const float* __restrict__ heat, const float* __restrict__ coords,
           const int* __restrict__ bidx, int N, int* __restrict__ topk) {
    __shared__ int   hist[NBINS];
    __shared__ float ch[NCAP], cxs[NCAP], cys[NCAP], czs[NCAP];
    __shared__ int   cid[NCAP];
    __shared__ int   sh_s, sh_e, sh_T, sh_cnt;
    __shared__ float sh_val;
    __shared__ float rv[16]; __shared__ int ri[16];
    __shared__ float fbx[32], fby[32], fbz[32];
    int b = blockIdx.x, tid = threadIdx.x;
    if (tid == 0) {
        int lo = 0, hi = N;
        while (lo < hi) { int m = (lo + hi) >> 1; if (bidx[m] < b) lo = m + 1; else hi = m; }
        sh_s = lo;
        lo = 0; hi = N;
        while (lo < hi) { int m = (lo + hi) >> 1; if (bidx[m] < b + 1) lo = m + 1; else hi = m; }
        sh_e = lo;
    }
    __syncthreads();
    int s = sh_s, e = sh_e, nb = e - s;
    if (nb <= 0) {
        if (tid < 32) topk[b * 32 + tid] = 0;
        return;
    }
    for (int i = tid; i < NBINS; i += 1024) hist[i] = 0;
    __syncthreads();
    for (int n = s + tid; n < e; n += 1024) {
        float h = heat[n];
        int bin = (int)(h * (float)NBINS);
        bin = min(max(bin, 0), NBINS - 1);
        atomicAdd(&hist[bin], 1);
    }
    __syncthreads();
    for (int off = 1; off < NBINS; off <<= 1) {
        int v[2];
#pragma unroll
        for (int u = 0; u < 2; u++) {
            int i = tid + u * 1024;
            v[u] = hist[i] + ((i + off < NBINS) ? hist[i + off] : 0);
        }
        __syncthreads();
#pragma unroll
        for (int u = 0; u < 2; u++) hist[tid + u * 1024] = v[u];
        __syncthreads();
    }
    int Meff = min(NMC, nb);
#pragma unroll
    for (int u = 0; u < 2; u++) {
        int i = tid + u * 1024;
        if (hist[i] >= Meff && (i == NBINS - 1 || hist[i + 1] < Meff)) sh_T = i;
    }
    if (tid == 0) sh_cnt = 0;
    __syncthreads();
    int T = sh_T;
    float thr = (float)T * (1.0f / (float)NBINS);
    for (int n = s + tid; n < e; n += 1024) {
        float h = heat[n];
        int bin = (int)(h * (float)NBINS);
        bin = min(max(bin, 0), NBINS - 1);
        if (bin >= T) {
            int p = atomicAdd(&sh_cnt, 1);
            if (p < NCAP) {
                ch[p] = h; cid[p] = n;
                cxs[p] = coords[(size_t)n * 3 + 0];
                cys[p] = coords[(size_t)n * 3 + 1];
                czs[p] = coords[(size_t)n * 3 + 2];
            }
        }
    }
    __syncthreads();
    int C = min(sh_cnt, NCAP);
    bool overflow = (sh_cnt > NCAP);
    if (tid < 64) {
        float hh[SLOTS], xx[SLOTS], yy[SLOTS], zz[SLOTS];
        int ii[SLOTS];
#pragma unroll
        for (int m = 0; m < SLOTS; m++) {
            int i = m * 64 + tid;
            if (i < C) { hh[m] = ch[i]; xx[m] = cxs[i]; yy[m] = cys[i]; zz[m] = czs[i]; ii[m] = cid[i]; }
            else { hh[m] = -INFINITY; xx[m] = 1e30f; yy[m] = 1e30f; zz[m] = 1e30f; ii[m] = INT_MAX; }
        }
        float last = -INFINITY;
        for (int t = 0; t < 32; t++) {
            float bv = -INFINITY, bx = 0.f, by = 0.f, bz = 0.f;
            int bo = INT_MAX;
#pragma unroll
            for (int m = 0; m < SLOTS; m++) {
                bool c = (hh[m] > bv) || (hh[m] == bv && ii[m] < bo);
                if (c) { bv = hh[m]; bo = ii[m]; bx = xx[m]; by = yy[m]; bz = zz[m]; }
            }
#pragma unroll
            for (int off = 32; off > 0; off >>= 1) {
                float ov = __shfl_down(bv, off);
                int   oo = __shfl_down(bo, off);
                float ox = __shfl_down(bx, off);
                float oy = __shfl_down(by, off);
                float oz = __shfl_down(bz, off);
                bool c = (ov > bv) || (ov == bv && oo < bo);
                if (c) { bv = ov; bo = oo; bx = ox; by = oy; bz = oz; }
            }
            bv = __shfl(bv, 0); bo = __shfl(bo, 0);
            bx = __shfl(bx, 0); by = __shfl(by, 0); bz = __shfl(bz, 0);
            if (tid == 0) topk[b * 32 + t] = bo;
            last = bv;
#pragma unroll
            for (int m = 0; m < SLOTS; m++) {
                float dx = xx[m] - bx, dy = yy[m] - by, dz = zz[m] - bz;
                if (dx * dx + dy * dy + dz * dz < R2C) hh[m] = -INFINITY;
            }
        }
        if (tid == 0) sh_val = last;
    }
    __syncthreads();
    bool sound = (!overflow) && (C > 0) && (sh_val >= thr);
    if (!sound) {
        for (int t = 0; t < 32; t++) {
            float bv = -INFINITY; int bo = INT_MAX;
            for (int n = s + tid; n < e; n += 1024) {
                float x = coords[(size_t)n * 3], y = coords[(size_t)n * 3 + 1], z = coords[(size_t)n * 3 + 2];
                bool sup = false;
                for (int u = 0; u < t; u++) {
                    float dx = x - fbx[u], dy = y - fby[u], dz = z - fbz[u];
                    if (dx * dx + dy * dy + dz * dz < R2C) { sup = true; break; }
                }
                if (!sup) {
                    float h = heat[n];
                    if (h > bv || (h == bv && n < bo)) { bv = h; bo = n; }
                }
            }
#pragma unroll
            for (int off = 32; off > 0; off >>= 1) {
                float ov = __shfl_down(bv, off); int oo = __shfl_down(bo, off);
                if (ov > bv || (ov == bv && oo < bo)) { bv = ov; bo = oo; }
            }
            if ((tid & 63) == 0) { int w = tid >> 6; rv[w] = bv; ri[w] = bo; }
            __syncthreads();
            if (tid == 0) {
                bv = rv[0]; bo = ri[0];
                for (int w = 1; w < 16; w++)
                    if (rv[w] > bv || (rv[w] == bv && ri[w] < bo)) { bv = rv[w]; bo = ri[w]; }
                if (bo == INT_MAX) bo = 0;
                topk[b * 32 + t] = bo;
                fbx[t] = coords[(size_t)bo * 3];
                fby[t] = coords[(size_t)bo * 3 + 1];
                fbz[t] = coords[(size_t)bo * 3 + 2];
            }
            __syncthreads();
        }
    }
}

// ============================ instance prep ===============================
__global__ __launch_bounds__(384)
void k_prep(const int* __restrict__ topk, const float* __restrict__ coords,
            const int* __restrict__ bidx, const float* __restrict__ maskf,
            const float* __restrict__ kernf, const float* __restrict__ Wwg,
            const float* __restrict__ bwg, float* __restrict__ Vt,
            float* __restrict__ featw, int* __restrict__ cand_batch) {
    __shared__ float ck[16], cm[16], ctr[3], wrow[337];
    int i = blockIdx.x, tid = threadIdx.x;
    int idx = topk[i];
    if (tid < 16) { ck[tid] = kernf[(size_t)idx * 16 + tid]; cm[tid] = maskf[(size_t)idx * 16 + tid]; }
    else if (tid < 19) ctr[tid - 16] = coords[(size_t)idx * 3 + (tid - 16)];
    else if (tid == 19) cand_batch[i] = bidx[idx];
    __syncthreads();
    for (int c = tid; c < 337; c += 384) {
        float acc = bwg[c];
#pragma unroll
        for (int m = 0; m < 16; m++) acc += ck[m] * Wwg[m * 337 + c];
        wrow[c] = acc;
    }
    __syncthreads();
    for (int t = tid; t < 352; t += 384) {
        float v;
        if (t < 320) {
            int k = t >> 4, j = t & 15;
            if (k < 19) v = wrow[k * 16 + j];
            else {
                v = wrow[304 + j];
#pragma unroll
                for (int p = 0; p < 3; p++) v -= ctr[p] * wrow[(16 + p) * 16 + j];
            }
        } else if (t < 336) v = wrow[320 + (t - 320)];
        else if (t == 336) v = wrow[336];
        else v = 0.f;
        Vt[(size_t)i * 352 + t] = v;
    }
    for (int t = tid; t < 36; t += 384)
        featw[i * 36 + t] = (t < 16) ? ck[t] : (t < 32) ? cm[t - 16] : (t < 35) ? ctr[t - 32] : 0.f;
}

// ============================== mask heads ================================
// CROSS-THREAD LDS staging: thread tid loads the activations of point
// (tid+1)&255 and writes column (tid+1)&255; after __syncthreads, thread tid
// reads column tid -- data produced by its NEIGHBOR. Round 9 proved the
// same-thread staging gets store-to-load-forwarded and the LDS deleted
// (counters: LDS_Block_Size=0, VGPR=20, FETCH 31MB remat reloads). A
// cross-thread dependency through LDS cannot be forwarded or rematerialized.
// Inner loop: 1 ds_read_b32 + 4 s_load_dwordx4 feed 16 fma.
#define MASK_PER 16
#define MROW(K) { float a = al[(K) * 256]; \
    float4 w0 = V4[(K)*4], w1 = V4[(K)*4+1], w2 = V4[(K)*4+2], w3 = V4[(K)*4+3]; \
    h0 = fmaf(a, w0.x, h0);  h1 = fmaf(a, w0.y, h1);  h2 = fmaf(a, w0.z, h2);  h3 = fmaf(a, w0.w, h3); \
    h4 = fmaf(a, w1.x, h4);  h5 = fmaf(a, w1.y, h5);  h6 = fmaf(a, w1.z, h6);  h7 = fmaf(a, w1.w, h7); \
    h8 = fmaf(a, w2.x, h8);  h9 = fmaf(a, w2.y, h9);  h10 = fmaf(a, w2.z, h10); h11 = fmaf(a, w2.w, h11); \
    h12 = fmaf(a, w3.x, h12); h13 = fmaf(a, w3.y, h13); h14 = fmaf(a, w3.z, h14); h15 = fmaf(a, w3.w, h15); }
__global__ __launch_bounds__(256)
void k_mask(const float* __restrict__ maskf, const float* __restrict__ coords,
            const float* __restrict__ Vt, float* __restrict__ out,
            int N, int ostride) {
    __shared__ float als[20 * 256];
    int tid = threadIdx.x;
    {
        // loader role: handle column lt = (tid+1)&255 (still coalesced, rotated by 1)
        int lt = (tid + 1) & 255;
        int nl = blockIdx.x * 256 + lt;
        int cl = (nl < N) ? nl : (N - 1);
        const float4* fr = (const float4*)(maskf + (size_t)cl * 16);
        float4 P = fr[0], Q = fr[1], R = fr[2], S = fr[3];
        als[0*256+lt]=P.x;  als[1*256+lt]=P.y;  als[2*256+lt]=P.z;  als[3*256+lt]=P.w;
        als[4*256+lt]=Q.x;  als[5*256+lt]=Q.y;  als[6*256+lt]=Q.z;  als[7*256+lt]=Q.w;
        als[8*256+lt]=R.x;  als[9*256+lt]=R.y;  als[10*256+lt]=R.z; als[11*256+lt]=R.w;
        als[12*256+lt]=S.x; als[13*256+lt]=S.y; als[14*256+lt]=S.z; als[15*256+lt]=S.w;
        als[16*256+lt]=coords[(size_t)cl*3];
        als[17*256+lt]=coords[(size_t)cl*3+1];
        als[18*256+lt]=coords[(size_t)cl*3+2];
        als[19*256+lt]=1.f;
    }
    __syncthreads();
    int n = blockIdx.x * 256 + tid;
    bool valid = (n < N);
    const float* al = als + tid;
    int ibase = blockIdx.y * MASK_PER;
    const float4* __restrict__ V4 = (const float4*)(Vt + (size_t)ibase * 352);  // block-uniform
    float* op = out + (size_t)ibase * ostride + n;
    for (int ii = 0; ii < MASK_PER; ii++) {
        float h0=0.f,h1=0.f,h2=0.f,h3=0.f,h4=0.f,h5=0.f,h6=0.f,h7=0.f;
        float h8=0.f,h9=0.f,h10=0.f,h11=0.f,h12=0.f,h13=0.f,h14=0.f,h15=0.f;
        MROW(0)  MROW(1)  MROW(2)  MROW(3)  MROW(4)
        MROW(5)  MROW(6)  MROW(7)  MROW(8)  MROW(9)
        MROW(10) MROW(11) MROW(12) MROW(13) MROW(14)
        MROW(15) MROW(16) MROW(17) MROW(18) MROW(19)
        float4 u0 = V4[80], u1 = V4[81], u2 = V4[82], u3 = V4[83];
        float acc = V4[84].x;               // V[336] = b2
        acc = fmaf(fmaxf(h0, 0.f),  u0.x, acc);
        acc = fmaf(fmaxf(h1, 0.f),  u0.y, acc);
        acc = fmaf(fmaxf(h2, 0.f),  u0.z, acc);
        acc = fmaf(fmaxf(h3, 0.f),  u0.w, acc);
        acc = fmaf(fmaxf(h4, 0.f),  u1.x, acc);
        acc = fmaf(fmaxf(h5, 0.f),  u1.y, acc);
        acc = fmaf(fmaxf(h6, 0.f),  u1.z, acc);
        acc = fmaf(fmaxf(h7, 0.f),  u1.w, acc);
        acc = fmaf(fmaxf(h8, 0.f),  u2.x, acc);
        acc = fmaf(fmaxf(h9, 0.f),  u2.y, acc);
        acc = fmaf(fmaxf(h10, 0.f), u2.z, acc);
        acc = fmaf(fmaxf(h11, 0.f), u2.w, acc);
        acc = fmaf(fmaxf(h12, 0.f), u3.x, acc);
        acc = fmaf(fmaxf(h13, 0.f), u3.y, acc);
        acc = fmaf(fmaxf(h14, 0.f), u3.z, acc);
        acc = fmaf(fmaxf(h15, 0.f), u3.w, acc);
        if (valid) *op = 1.f / (1.f + __expf(-acc));
        V4 += 88;                            // 352/4
        op += ostride;
    }
}

// ============================== merge tower ===============================
// Split chain (stream boundaries = free device-wide visibility, no barrier,
// no atomics). Z is COLUMN-MAJOR Z[j*16384+id] (coalesced); normalize fused
// on the fly (no x[] array); z[35] statically indexed, fully unrolled.
#define MROWS 16384
__global__ __launch_bounds__(256)
void k_merge1(const float* __restrict__ featw, const float* __restrict__ Wg,
              float* __restrict__ Z, double* __restrict__ pout) {
    __shared__ float F[128 * 36];
    __shared__ double redm[280];
    int tid = threadIdx.x;
    for (int t = tid; t < 128 * 36; t += 256) F[t] = featw[t];
    __syncthreads();
    int id = blockIdx.x * 256 + tid;
    int a = id >> 7, b = id & 127;
    float z[35];
#pragma unroll
    for (int j = 0; j < 35; j++) z[j] = 0.f;
#pragma unroll
    for (int k = 0; k < 35; k++) {
        float dk = fmaxf(fabsf(F[a * 36 + k] - F[b * 36 + k]), 1e-6f);
        const float* wr = Wg + k * 35;        // wave-uniform -> s_loads
#pragma unroll
        for (int j = 0; j < 35; j++) z[j] = fmaf(dk, wr[j], z[j]);
    }
    int wv = tid >> 6;
#pragma unroll
    for (int j = 0; j < 35; j++) {
        float s = z[j], q = z[j] * z[j];
#pragma unroll
        for (int off = 32; off > 0; off >>= 1) { s += __shfl_down(s, off); q += __shfl_down(q, off); }
        if ((tid & 63) == 0) { redm[wv * 70 + j] = (double)s; redm[wv * 70 + 35 + j] = (double)q; }
    }
    __syncthreads();
    if (tid < 70) {
        double t = redm[tid] + redm[70 + tid] + redm[140 + tid] + redm[210 + tid];
        pout[(size_t)blockIdx.x * 70 + tid] = t;
    }
#pragma unroll
    for (int j = 0; j < 35; j++) Z[(size_t)j * MROWS + id] = z[j];   // coalesced
}

__global__ __launch_bounds__(256)
void k_merge_mid(const float* __restrict__ Zin, const float* __restrict__ Wg,
                 float* __restrict__ Zout, const double* __restrict__ pin,
                 double* __restrict__ pout) {
    __shared__ float nrm[70];
    __shared__ double sred[70];
    __shared__ double redm[280];
    int tid = threadIdx.x;
    if (tid < 70) {
        double a0 = 0.0, a1 = 0.0, a2 = 0.0, a3 = 0.0;
#pragma unroll
        for (int b = 0; b < 64; b += 4) {
            a0 += pin[(size_t)b * 70 + tid];
            a1 += pin[(size_t)(b + 1) * 70 + tid];
            a2 += pin[(size_t)(b + 2) * 70 + tid];
            a3 += pin[(size_t)(b + 3) * 70 + tid];
        }
        sred[tid] = (a0 + a1) + (a2 + a3);
    }
    __syncthreads();
    if (tid < 35) {
        double m = sred[tid] * (1.0 / 16384.0);
        double v = sred[35 + tid] * (1.0 / 16384.0) - m * m;
        nrm[tid] = (float)m; nrm[35 + tid] = (float)rsqrt(v + (double)EPSB);
    }
    __syncthreads();
    int id = blockIdx.x * 256 + tid;
    float z[35];
#pragma unroll
    for (int j = 0; j < 35; j++) z[j] = 0.f;
#pragma unroll
    for (int k = 0; k < 35; k++) {
        float zk = Zin[(size_t)k * MROWS + id];            // coalesced
        float dk = fmaxf((zk - nrm[k]) * nrm[35 + k], 0.f); // fused normalize
        const float* wr = Wg + k * 35;
#pragma unroll
        for (int j = 0; j < 35; j++) z[j] = fmaf(dk, wr[j], z[j]);
    }
    int wv = tid >> 6;
#pragma unroll
    for (int j = 0; j < 35; j++) {
        float s = z[j], q = z[j] * z[j];
#pragma unroll
        for (int off = 32; off > 0; off >>= 1) { s += __shfl_down(s, off); q += __shfl_down(q, off); }
        if ((tid & 63) == 0) { redm[wv * 70 + j] = (double)s; redm[wv * 70 + 35 + j] = (double)q; }
    }
    __syncthreads();
    if (tid < 70) {
        double t = redm[tid] + redm[70 + tid] + redm[140 + tid] + redm[210 + tid];
        pout[(size_t)blockIdx.x * 70 + tid] = t;
    }
#pragma unroll
    for (int j = 0; j < 35; j++) Zout[(size_t)j * MROWS + id] = z[j];
}

__global__ __launch_bounds__(256)
void k_merge_out(const float* __restrict__ Zin, const float* __restrict__ Wout,
                 const float* __restrict__ bout, const double* __restrict__ pin,
                 const int* __restrict__ cand_batch, float* __restrict__ out,
                 int N, int ostride) {
    __shared__ float nrm[70];
    __shared__ double sred[70];
    __shared__ int cb[128];
    int tid = threadIdx.x;
    if (tid < 70) {
        double a0 = 0.0, a1 = 0.0, a2 = 0.0, a3 = 0.0;
#pragma unroll
        for (int b = 0; b < 64; b += 4) {
            a0 += pin[(size_t)b * 70 + tid];
            a1 += pin[(size_t)(b + 1) * 70 + tid];
            a2 += pin[(size_t)(b + 2) * 70 + tid];
            a3 += pin[(size_t)(b + 3) * 70 + tid];
        }
        sred[tid] = (a0 + a1) + (a2 + a3);
    }
    if (tid >= 128 && tid < 256) cb[tid - 128] = cand_batch[tid - 128];
    __syncthreads();
    if (tid < 35) {
        double m = sred[tid] * (1.0 / 16384.0);
        double v = sred[35 + tid] * (1.0 / 16384.0) - m * m;
        nrm[tid] = (float)m; nrm[35 + tid] = (float)rsqrt(v + (double)EPSB);
    }
    __syncthreads();
    int id = blockIdx.x * 256 + tid;
    int a = id >> 7, b = id & 127;
    float s = bout[0];
#pragma unroll
    for (int k = 0; k < 35; k++) {
        float zk = Zin[(size_t)k * MROWS + id];            // coalesced
        s = fmaf(fmaxf((zk - nrm[k]) * nrm[35 + k], 0.f), Wout[k], s);
    }
    float v = 1.f / (1.f + __expf(-s));
    if (cb[a] != cb[b]) v = 0.f;
    out[(size_t)a * ostride + N + b] = v;
}

// =============================== launcher =================================
extern "C" void kernel_launch(void* const* d_in, const int* in_sizes, int n_in,
                              void* d_out, int out_size, void* d_ws, size_t ws_size,
                              hipStream_t stream) {
    const float* of     = (const float*)d_in[0];
    const float* coords = (const float*)d_in[1];
    const float* heat   = (const float*)d_in[2];
    const int*   bidx   = (const int*)d_in[3];
    const float* Wm     = (const float*)d_in[4];
    const float* Wm_out = (const float*)d_in[5];
    const float* bm_out = (const float*)d_in[6];
    const float* Wk     = (const float*)d_in[7];
    const float* Wk_out = (const float*)d_in[8];
    const float* bk_out = (const float*)d_in[9];
    const float* Wg     = (const float*)d_in[10];
    const float* Wg_out = (const float*)d_in[11];
    const float* bg_out = (const float*)d_in[12];
    const float* Wwg    = (const float*)d_in[13];
    const float* bwg    = (const float*)d_in[14];
    float* out = (float*)d_out;
    float* ws  = (float*)d_ws;

    int N = in_sizes[0] / 32;          // 100000
    int ostride = N + 128;             // 100128

    float*  maskf = ws + OFF_MASKF;
    float*  kernf = ws + OFF_KERNF;
    float*  Vt    = ws + OFF_VT;
    float*  featw = ws + OFF_FEATW;
    int*    topk  = (int*)(ws + OFF_INT);
    int*    cand_batch = topk + 128;

    // tower BN partials ping-pong in mz1 region:
    double* TPA = (double*)(ws + OFF_MZ1);
    double* TPB = (double*)(ws + OFF_MZ1 + 131072);
    // merge BN partials in kernf region (dead after k_prep):
    double* P1 = (double*)(ws + OFF_KERNF);
    double* P2 = (double*)(ws + OFF_KERNF + 16384);
    double* P3 = (double*)(ws + OFF_KERNF + 32768);

    // tower ping-pong buffers live inside d_out (dead after towers);
    // merge Z ping-pong reuses d_out scratch too (merge runs BEFORE k_mask,
    // which then overwrites columns 0..N; merge output cols N..N+128 survive).
    float* bufAm = out;
    float* bufBm = out + (size_t)N * 32;
    float* bufAk = out + (size_t)N * 64;
    float* bufBk = out + (size_t)N * 96;
    float* Za    = out + (size_t)N * 64;   // 573440 floats < N*32
    float* Zb    = out + (size_t)N * 96;

    dim3 tg2((N + 255) / 256, 2);

    k_nms<<<4, 1024, 0, stream>>>(heat, coords, bidx, N, topk);
    k_tower2<32><<<tg2, 256, 0, stream>>>(of,    of,    Wm,        Wk,        nullptr, nullptr, bufAm, bufAk, nullptr, TPA,     N);
    k_tower2<32><<<tg2, 256, 0, stream>>>(bufAm, bufAk, Wm + 1024, Wk + 1024, nullptr, nullptr, bufBm, bufBk, TPA,     TPB,     N);
    k_tower2<32><<<tg2, 256, 0, stream>>>(bufBm, bufBk, Wm + 2048, Wk + 2048, nullptr, nullptr, bufAm, bufAk, TPB,     TPA,     N);
    k_tower2<16><<<tg2, 256, 0, stream>>>(bufAm, bufAk, Wm_out,    Wk_out,    bm_out,  bk_out,  maskf, kernf, TPA,     nullptr, N);

    k_prep<<<128, 384, 0, stream>>>(topk, coords, bidx, maskf, kernf, Wwg, bwg,
                                    Vt, featw, cand_batch);

    // merge chain first (Z scratch in d_out), then mask overwrites cols 0..N
    k_merge1<<<64, 256, 0, stream>>>(featw, Wg, Za, P1);
    k_merge_mid<<<64, 256, 0, stream>>>(Za, Wg + 1225, Zb, P1, P2);
    k_merge_mid<<<64, 256, 0, stream>>>(Zb, Wg + 2450, Za, P2, P3);
    k_merge_out<<<64, 256, 0, stream>>>(Za, Wg_out, bg_out, P3, cand_batch,
                                        out, N, ostride);

    k_mask<<<dim3((N + 255) / 256, 8), 256, 0, stream>>>(maskf, coords, Vt, out, N, ostride);
}

// Round 11
// 654.871 us; speedup vs baseline: 1.0156x; 1.0092x over previous
//
#include <hip/hip_runtime.h>
#include <math.h>
#include <limits.h>

#define EPSB 1e-5f
#define R2C  0.09f

// ---- workspace offsets (floats). Total ~4.44M floats = ~17.8 MB ----
#define OFF_MASKF 0          // N*16
#define OFF_KERNF 1600000    // N*16  (dead after k_prep -> merge partials live here)
#define OFF_STATS 3200000    // (unused)
#define OFF_VT    3202048    // 128*352
#define OFF_FEATW 3247104    // 128*36
#define OFF_MZ1   3251712    // tower partials (dead after towers) -> merge Za
#define OFF_MZ2   3841536    // merge Zb
#define OFF_INT   4431360    // 256 ints (topk 128 | cand_batch 128)

// ============================ fused tower layer ===========================
// blockIdx.y = tower (0: mask, 1: kernel).
// BN stats: producer blocks write per-block partial (sum,sumsq) rows
// NON-ATOMICALLY to tp_out[(tw*gridDim.x + blk)*64 + {0..63}]; consumer
// reduces at head with 4 independent fp64 accumulators (loads pipeline).
// Stats computed from the As stage-out tile via LDS column sums.
template <int COLS>
__global__ __launch_bounds__(256)
void k_tower2(const float* __restrict__ X0, const float* __restrict__ X1,
              const float* __restrict__ W0, const float* __restrict__ W1,
              const float* __restrict__ b0, const float* __restrict__ b1,
              float* __restrict__ Y0, float* __restrict__ Y1,
              const double* __restrict__ tp_in, double* __restrict__ tp_out,
              int N) {
    __shared__ float As[256 * 33];
    __shared__ float mrs[64];
    __shared__ float redS[256];
    __shared__ float redQ[256];
    __shared__ double redd[256];
    int tid = threadIdx.x;
    int tw = blockIdx.y;
    const float* X = tw ? X1 : X0;
    const float* W = tw ? W1 : W0;
    const float* bias = tw ? b1 : b0;
    float* Y = tw ? Y1 : Y0;

    bool nrm = (tp_in != nullptr);
    if (nrm) {
        int col = tid & 63, part = tid >> 6;
        const double* src = tp_in + (size_t)tw * gridDim.x * 64 + col;
        int nb = (int)gridDim.x;
        double a0 = 0.0, a1 = 0.0, a2 = 0.0, a3 = 0.0;
        int b = part;
        for (; b + 12 < nb; b += 16) {
            a0 += src[(size_t)b * 64];
            a1 += src[(size_t)(b + 4) * 64];
            a2 += src[(size_t)(b + 8) * 64];
            a3 += src[(size_t)(b + 12) * 64];
        }
        for (; b < nb; b += 4) a0 += src[(size_t)b * 64];
        redd[part * 64 + col] = (a0 + a1) + (a2 + a3);
        __syncthreads();
        if (tid < 32) {
            double S = redd[tid] + redd[64 + tid] + redd[128 + tid] + redd[192 + tid];
            double Q = redd[32 + tid] + redd[96 + tid] + redd[160 + tid] + redd[224 + tid];
            double m = S / (double)N;
            double v = Q / (double)N - m * m;
            mrs[tid] = (float)m; mrs[32 + tid] = (float)rsqrt(v + (double)EPSB);
        }
    }
    __syncthreads();
    int rbase = blockIdx.x * 256;
    int rmax = N - rbase; if (rmax > 256) rmax = 256;
    const float4* Xv = (const float4*)(X + (size_t)rbase * 32);
    for (int f = tid; f < 2048; f += 256) {
        int r = f >> 3, c0 = (f & 7) * 4;
        float4 v = make_float4(0.f, 0.f, 0.f, 0.f);
        if (r < rmax) v = Xv[f];
        float e[4] = {v.x, v.y, v.z, v.w};
        float* dst = &As[r * 33 + c0];
#pragma unroll
        for (int u = 0; u < 4; u++) {
            float t = e[u];
            if (nrm) t = fmaxf((t - mrs[c0 + u]) * mrs[32 + c0 + u], 0.f);
            dst[u] = t;
        }
    }
    __syncthreads();
    float acc[COLS];
#pragma unroll
    for (int j = 0; j < COLS; j++) acc[j] = 0.f;
    if (bias) {
#pragma unroll
        for (int j = 0; j < COLS; j++) acc[j] = bias[j];
    }
#pragma unroll 4
    for (int k = 0; k < 32; k++) {
        float a = As[tid * 33 + k];
        const float* wr = W + k * COLS;   // wave-uniform -> scalar loads
#pragma unroll
        for (int j = 0; j < COLS; j++) acc[j] = fmaf(a, wr[j], acc[j]);
    }
    __syncthreads();
#pragma unroll
    for (int j = 0; j < COLS; j++) As[tid * 33 + j] = acc[j];
    __syncthreads();
    constexpr int C4 = COLS / 4;
    for (int f = tid; f < 256 * C4; f += 256) {
        int r = f / C4, c0 = (f % C4) * 4;
        if (r < rmax) {
            const float* sp = &As[r * 33 + c0];
            float4 o = {sp[0], sp[1], sp[2], sp[3]};
            *(float4*)(Y + (size_t)(rbase + r) * COLS + c0) = o;
        }
    }
    if constexpr (COLS == 32) {
        if (tp_out) {
            int j = tid & 31, g = tid >> 5;     // 8 groups x 32 rows each
            float s = 0.f, q = 0.f;
#pragma unroll
            for (int i = 0; i < 32; i++) {
                float v = As[(g * 32 + i) * 33 + j];   // bank (i+j)%32: conflict-free
                s += v; q = fmaf(v, v, q);
            }
            redS[tid] = s; redQ[tid] = q;
            __syncthreads();
            if (tid < 64) {
                int jj = tid & 31;
                const float* rp = (tid < 32) ? redS : redQ;
                double acc2 = 0.0;
#pragma unroll
                for (int g2 = 0; g2 < 8; g2++) acc2 += (double)rp[g2 * 32 + jj];
                tp_out[((size_t)tw * gridDim.x + blockIdx.x) * 64 + tid] = acc2;
            }
        }
    }
}

// ================================= NMS ====================================
#define NBINS 2048
#define NMC   1024
#define NCAP  1088
#define SLOTS 17
__global__ __launch_bounds__(1024)
void k_nms(const float* __restrict__ heat, const float* __restrict__ coords,
           const int* __restrict__ bidx, int N, int* __restrict__ topk) {
    __shared__ int   hist[NBINS];
    __shared__ float ch[NCAP], cxs[NCAP], cys[NCAP], czs[NCAP];
    __shared__ int   cid[NCAP];
    __shared__ int   sh_s, sh_e, sh_T, sh_cnt;
    __shared__ float sh_val;
    __shared__ float rv[16]; __shared__ int ri[16];
    __shared__ float fbx[32], fby[32], fbz[32];
    int b = blockIdx.x, tid = threadIdx.x;
    if (tid == 0) {
        int lo = 0, hi = N;
        while (lo < hi) { int m = (lo + hi) >> 1; if (bidx[m] < b) lo = m + 1; else hi = m; }
        sh_s = lo;
        lo = 0; hi = N;
        while (lo < hi) { int m = (lo + hi) >> 1; if (bidx[m] < b + 1) lo = m + 1; else hi = m; }
        sh_e = lo;
    }
    __syncthreads();
    int s = sh_s, e = sh_e, nb = e - s;
    if (nb <= 0) {
        if (tid < 32) topk[b * 32 + tid] = 0;
        return;
    }
    for (int i = tid; i < NBINS; i += 1024) hist[i] = 0;
    __syncthreads();
    for (int n = s + tid; n < e; n += 1024) {
        float h = heat[n];
        int bin = (int)(h * (float)NBINS);
        bin = min(max(bin, 0), NBINS - 1);
        atomicAdd(&hist[bin], 1);
    }
    __syncthreads();
    for (int off = 1; off < NBINS; off <<= 1) {
        int v[2];
#pragma unroll
        for (int u = 0; u < 2; u++) {
            int i = tid + u * 1024;
            v[u] = hist[i] + ((i + off < NBINS) ? hist[i + off] : 0);
        }
        __syncthreads();
#pragma unroll
        for (int u = 0; u < 2; u++) hist[tid + u * 1024] = v[u];
        __syncthreads();
    }
    int Meff = min(NMC, nb);
#pragma unroll
    for (int u = 0; u < 2; u++) {
        int i = tid + u * 1024;
        if (hist[i] >= Meff && (i == NBINS - 1 || hist[i + 1] < Meff)) sh_T = i;
    }
    if (tid == 0) sh_cnt = 0;
    __syncthreads();
    int T = sh_T;
    float thr = (float)T * (1.0f / (float)NBINS);
    for (int n = s + tid; n < e; n += 1024) {
        float h = heat[n];
        int bin = (int)(h * (float)NBINS);
        bin = min(max(bin, 0), NBINS - 1);
        if (bin >= T) {
            int p = atomicAdd(&sh_cnt, 1);
            if (p < NCAP) {
                ch[p] = h; cid[p] = n;
                cxs[p] = coords[(size_t)n * 3 + 0];
                cys[p] = coords[(size_t)n * 3 + 1];
                czs[p] = coords[(size_t)n * 3 + 2];
            }
        }
    }
    __syncthreads();
    int C = min(sh_cnt, NCAP);
    bool overflow = (sh_cnt > NCAP);
    if (tid < 64) {
        float hh[SLOTS], xx[SLOTS], yy[SLOTS], zz[SLOTS];
        int ii[SLOTS];
#pragma unroll
        for (int m = 0; m < SLOTS; m++) {
            int i = m * 64 + tid;
            if (i < C) { hh[m] = ch[i]; xx[m] = cxs[i]; yy[m] = cys[i]; zz[m] = czs[i]; ii[m] = cid[i]; }
            else { hh[m] = -INFINITY; xx[m] = 1e30f; yy[m] = 1e30f; zz[m] = 1e30f; ii[m] = INT_MAX; }
        }
        float last = -INFINITY;
        for (int t = 0; t < 32; t++) {
            float bv = -INFINITY, bx = 0.f, by = 0.f, bz = 0.f;
            int bo = INT_MAX;
#pragma unroll
            for (int m = 0; m < SLOTS; m++) {
                bool c = (hh[m] > bv) || (hh[m] == bv && ii[m] < bo);
                if (c) { bv = hh[m]; bo = ii[m]; bx = xx[m]; by = yy[m]; bz = zz[m]; }
            }
#pragma unroll
            for (int off = 32; off > 0; off >>= 1) {
                float ov = __shfl_down(bv, off);
                int   oo = __shfl_down(bo, off);
                float ox = __shfl_down(bx, off);
                float oy = __shfl_down(by, off);
                float oz = __shfl_down(bz, off);
                bool c = (ov > bv) || (ov == bv && oo < bo);
                if (c) { bv = ov; bo = oo; bx = ox; by = oy; bz = oz; }
            }
            bv = __shfl(bv, 0); bo = __shfl(bo, 0);
            bx = __shfl(bx, 0); by = __shfl(by, 0); bz = __shfl(bz, 0);
            if (tid == 0) topk[b * 32 + t] = bo;
            last = bv;
#pragma unroll
            for (int m = 0; m < SLOTS; m++) {
                float dx = xx[m] - bx, dy = yy[m] - by, dz = zz[m] - bz;
                if (dx * dx + dy * dy + dz * dz < R2C) hh[m] = -INFINITY;
            }
        }
        if (tid == 0) sh_val = last;
    }
    __syncthreads();
    bool sound = (!overflow) && (C > 0) && (sh_val >= thr);
    if (!sound) {
        for (int t = 0; t < 32; t++) {
            float bv = -INFINITY; int bo = INT_MAX;
            for (int n = s + tid; n < e; n += 1024) {
                float x = coords[(size_t)n * 3], y = coords[(size_t)n * 3 + 1], z = coords[(size_t)n * 3 + 2];
                bool sup = false;
                for (int u = 0; u < t; u++) {
                    float dx = x - fbx[u], dy = y - fby[u], dz = z - fbz[u];
                    if (dx * dx + dy * dy + dz * dz < R2C) { sup = true; break; }
                }
                if (!sup) {
                    float h = heat[n];
                    if (h > bv || (h == bv && n < bo)) { bv = h; bo = n; }
                }
            }
#pragma unroll
            for (int off = 32; off > 0; off >>= 1) {
                float ov = __shfl_down(bv, off); int oo = __shfl_down(bo, off);
                if (ov > bv || (ov == bv && oo < bo)) { bv = ov; bo = oo; }
            }
            if ((tid & 63) == 0) { int w = tid >> 6; rv[w] = bv; ri[w] = bo; }
            __syncthreads();
            if (tid == 0) {
                bv = rv[0]; bo = ri[0];
                for (int w = 1; w < 16; w++)
                    if (rv[w] > bv || (rv[w] == bv && ri[w] < bo)) { bv = rv[w]; bo = ri[w]; }
                if (bo == INT_MAX) bo = 0;
                topk[b * 32 + t] = bo;
                fbx[t] = coords[(size_t)bo * 3];
                fby[t] = coords[(size_t)bo * 3 + 1];
                fbz[t] = coords[(size_t)bo * 3 + 2];
            }
            __syncthreads();
        }
    }
}

// ============================ instance prep ===============================
__global__ __launch_bounds__(384)
void k_prep(const int* __restrict__ topk, const float* __restrict__ coords,
            const int* __restrict__ bidx, const float* __restrict__ maskf,
            const float* __restrict__ kernf, const float* __restrict__ Wwg,
            const float* __restrict__ bwg, float* __restrict__ Vt,
            float* __restrict__ featw, int* __restrict__ cand_batch) {
    __shared__ float ck[16], cm[16], ctr[3], wrow[337];
    int i = blockIdx.x, tid = threadIdx.x;
    int idx = topk[i];
    if (tid < 16) { ck[tid] = kernf[(size_t)idx * 16 + tid]; cm[tid] = maskf[(size_t)idx * 16 + tid]; }
    else if (tid < 19) ctr[tid - 16] = coords[(size_t)idx * 3 + (tid - 16)];
    else if (tid == 19) cand_batch[i] = bidx[idx];
    __syncthreads();
    for (int c = tid; c < 337; c += 384) {
        float acc = bwg[c];
#pragma unroll
        for (int m = 0; m < 16; m++) acc += ck[m] * Wwg[m * 337 + c];
        wrow[c] = acc;
    }
    __syncthreads();
    for (int t = tid; t < 352; t += 384) {
        float v;
        if (t < 320) {
            int k = t >> 4, j = t & 15;
            if (k < 19) v = wrow[k * 16 + j];
            else {
                v = wrow[304 + j];
#pragma unroll
                for (int p = 0; p < 3; p++) v -= ctr[p] * wrow[(16 + p) * 16 + j];
            }
        } else if (t < 336) v = wrow[320 + (t - 320)];
        else if (t == 336) v = wrow[336];
        else v = 0.f;
        Vt[(size_t)i * 352 + t] = v;
    }
    for (int t = tid; t < 36; t += 384)
        featw[i * 36 + t] = (t < 16) ? ck[t] : (t < 32) ? cm[t - 16] : (t < 35) ? ctr[t - 32] : 0.f;
}

// ============================== mask heads ================================
// Cross-thread LDS staging (kept from round 10 -- LDS survived, counters
// showed LDS_Block_Size=20480). NEW: 4 INSTANCES PER THREAD share each
// al[k] ds_read. Round 10 showed the compiler interchanges to j-outer and
// re-reads al per j-group (VGPR=20), making the loop ~1:1 ds_read:fma =
// LDS-pipe-bound (5.8cyc/ds vs 2cyc/fma -> 160us vs 57us VALU floor).
// With 4 instances amortizing each al read, even the WORST-CASE interchange
// is 1:4 ds:fma (LDS 7.4K cyc < VALU 10.2K cyc/wave) -> VALU-bound
// regardless of what the scheduler picks.
#define MASK_PER 16
#define QROW(K) { float a = al[(K) * 256]; \
    float4 wA = VA[(K)*4 + jg]; float4 wB = VB[(K)*4 + jg]; \
    float4 wC = VC[(K)*4 + jg]; float4 wD = VD[(K)*4 + jg]; \
    hA0 = fmaf(a, wA.x, hA0); hA1 = fmaf(a, wA.y, hA1); hA2 = fmaf(a, wA.z, hA2); hA3 = fmaf(a, wA.w, hA3); \
    hB0 = fmaf(a, wB.x, hB0); hB1 = fmaf(a, wB.y, hB1); hB2 = fmaf(a, wB.z, hB2); hB3 = fmaf(a, wB.w, hB3); \
    hC0 = fmaf(a, wC.x, hC0); hC1 = fmaf(a, wC.y, hC1); hC2 = fmaf(a, wC.z, hC2); hC3 = fmaf(a, wC.w, hC3); \
    hD0 = fmaf(a, wD.x, hD0); hD1 = fmaf(a, wD.y, hD1); hD2 = fmaf(a, wD.z, hD2); hD3 = fmaf(a, wD.w, hD3); }
__global__ __launch_bounds__(256)
void k_mask(const float* __restrict__ maskf, const float* __restrict__ coords,
            const float* __restrict__ Vt, float* __restrict__ out,
            int N, int ostride) {
    __shared__ float als[20 * 256];
    int tid = threadIdx.x;
    {
        // loader role: handle column lt = (tid+1)&255 (coalesced, rotated by 1)
        int lt = (tid + 1) & 255;
        int nl = blockIdx.x * 256 + lt;
        int cl = (nl < N) ? nl : (N - 1);
        const float4* fr = (const float4*)(maskf + (size_t)cl * 16);
        float4 P = fr[0], Q = fr[1], R = fr[2], S = fr[3];
        als[0*256+lt]=P.x;  als[1*256+lt]=P.y;  als[2*256+lt]=P.z;  als[3*256+lt]=P.w;
        als[4*256+lt]=Q.x;  als[5*256+lt]=Q.y;  als[6*256+lt]=Q.z;  als[7*256+lt]=Q.w;
        als[8*256+lt]=R.x;  als[9*256+lt]=R.y;  als[10*256+lt]=R.z; als[11*256+lt]=R.w;
        als[12*256+lt]=S.x; als[13*256+lt]=S.y; als[14*256+lt]=S.z; als[15*256+lt]=S.w;
        als[16*256+lt]=coords[(size_t)cl*3];
        als[17*256+lt]=coords[(size_t)cl*3+1];
        als[18*256+lt]=coords[(size_t)cl*3+2];
        als[19*256+lt]=1.f;
    }
    __syncthreads();
    int n = blockIdx.x * 256 + tid;
    bool valid = (n < N);
    const float* al = als + tid;
    int ibase = blockIdx.y * MASK_PER;
    for (int q = 0; q < 4; q++) {
        const float4* VA = (const float4*)(Vt + (size_t)(ibase + q * 4 + 0) * 352);
        const float4* VB = (const float4*)(Vt + (size_t)(ibase + q * 4 + 1) * 352);
        const float4* VC = (const float4*)(Vt + (size_t)(ibase + q * 4 + 2) * 352);
        const float4* VD = (const float4*)(Vt + (size_t)(ibase + q * 4 + 3) * 352);
        float accA = VA[84].x, accB = VB[84].x, accC = VC[84].x, accD = VD[84].x;
        for (int jg = 0; jg < 4; jg++) {
            float hA0=0.f,hA1=0.f,hA2=0.f,hA3=0.f;
            float hB0=0.f,hB1=0.f,hB2=0.f,hB3=0.f;
            float hC0=0.f,hC1=0.f,hC2=0.f,hC3=0.f;
            float hD0=0.f,hD1=0.f,hD2=0.f,hD3=0.f;
            QROW(0)  QROW(1)  QROW(2)  QROW(3)  QROW(4)
            QROW(5)  QROW(6)  QROW(7)  QROW(8)  QROW(9)
            QROW(10) QROW(11) QROW(12) QROW(13) QROW(14)
            QROW(15) QROW(16) QROW(17) QROW(18) QROW(19)
            float4 uA = VA[80 + jg], uB = VB[80 + jg];
            float4 uC = VC[80 + jg], uD = VD[80 + jg];
            accA = fmaf(fmaxf(hA0, 0.f), uA.x, accA);
            accA = fmaf(fmaxf(hA1, 0.f), uA.y, accA);
            accA = fmaf(fmaxf(hA2, 0.f), uA.z, accA);
            accA = fmaf(fmaxf(hA3, 0.f), uA.w, accA);
            accB = fmaf(fmaxf(hB0, 0.f), uB.x, accB);
            accB = fmaf(fmaxf(hB1, 0.f), uB.y, accB);
            accB = fmaf(fmaxf(hB2, 0.f), uB.z, accB);
            accB = fmaf(fmaxf(hB3, 0.f), uB.w, accB);
            accC = fmaf(fmaxf(hC0, 0.f), uC.x, accC);
            accC = fmaf(fmaxf(hC1, 0.f), uC.y, accC);
            accC = fmaf(fmaxf(hC2, 0.f), uC.z, accC);
            accC = fmaf(fmaxf(hC3, 0.f), uC.w, accC);
            accD = fmaf(fmaxf(hD0, 0.f), uD.x, accD);
            accD = fmaf(fmaxf(hD1, 0.f), uD.y, accD);
            accD = fmaf(fmaxf(hD2, 0.f), uD.z, accD);
            accD = fmaf(fmaxf(hD3, 0.f), uD.w, accD);
        }
        if (valid) {
            float* o = out + (size_t)(ibase + q * 4) * ostride + n;
            o[0]                    = 1.f / (1.f + __expf(-accA));
            o[(size_t)ostride]      = 1.f / (1.f + __expf(-accB));
            o[(size_t)ostride * 2]  = 1.f / (1.f + __expf(-accC));
            o[(size_t)ostride * 3]  = 1.f / (1.f + __expf(-accD));
        }
    }
}

// ============================== merge tower ===============================
// Split chain (stream boundaries = free device-wide visibility, no barrier,
// no atomics). Z is COLUMN-MAJOR Z[j*16384+id] (coalesced); normalize fused
// on the fly (no x[] array); z[35] statically indexed, fully unrolled.
// Za/Zb live in WORKSPACE (OFF_MZ1/OFF_MZ2): round 9/10 had them in d_out
// where k_merge_out's writes (rows 64-70, cols N..N+128) landed INSIDE the
// Za region it was concurrently reading -- a latent race that passed on
// timing luck only.
#define MROWS 16384
__global__ __launch_bounds__(256)
void k_merge1(const float* __restrict__ featw, const float* __restrict__ Wg,
              float* __restrict__ Z, double* __restrict__ pout) {
    __shared__ float F[128 * 36];
    __shared__ double redm[280];
    int tid = threadIdx.x;
    for (int t = tid; t < 128 * 36; t += 256) F[t] = featw[t];
    __syncthreads();
    int id = blockIdx.x * 256 + tid;
    int a = id >> 7, b = id & 127;
    float z[35];
#pragma unroll
    for (int j = 0; j < 35; j++) z[j] = 0.f;
#pragma unroll
    for (int k = 0; k < 35; k++) {
        float dk = fmaxf(fabsf(F[a * 36 + k] - F[b * 36 + k]), 1e-6f);
        const float* wr = Wg + k * 35;        // wave-uniform -> s_loads
#pragma unroll
        for (int j = 0; j < 35; j++) z[j] = fmaf(dk, wr[j], z[j]);
    }
    int wv = tid >> 6;
#pragma unroll
    for (int j = 0; j < 35; j++) {
        float s = z[j], q = z[j] * z[j];
#pragma unroll
        for (int off = 32; off > 0; off >>= 1) { s += __shfl_down(s, off); q += __shfl_down(q, off); }
        if ((tid & 63) == 0) { redm[wv * 70 + j] = (double)s; redm[wv * 70 + 35 + j] = (double)q; }
    }
    __syncthreads();
    if (tid < 70) {
        double t = redm[tid] + redm[70 + tid] + redm[140 + tid] + redm[210 + tid];
        pout[(size_t)blockIdx.x * 70 + tid] = t;
    }
#pragma unroll
    for (int j = 0; j < 35; j++) Z[(size_t)j * MROWS + id] = z[j];   // coalesced
}

__global__ __launch_bounds__(256)
void k_merge_mid(const float* __restrict__ Zin, const float* __restrict__ Wg,
                 float* __restrict__ Zout, const double* __restrict__ pin,
                 double* __restrict__ pout) {
    __shared__ float nrm[70];
    __shared__ double sred[70];
    __shared__ double redm[280];
    int tid = threadIdx.x;
    if (tid < 70) {
        double a0 = 0.0, a1 = 0.0, a2 = 0.0, a3 = 0.0;
#pragma unroll
        for (int b = 0; b < 64; b += 4) {
            a0 += pin[(size_t)b * 70 + tid];
            a1 += pin[(size_t)(b + 1) * 70 + tid];
            a2 += pin[(size_t)(b + 2) * 70 + tid];
            a3 += pin[(size_t)(b + 3) * 70 + tid];
        }
        sred[tid] = (a0 + a1) + (a2 + a3);
    }
    __syncthreads();
    if (tid < 35) {
        double m = sred[tid] * (1.0 / 16384.0);
        double v = sred[35 + tid] * (1.0 / 16384.0) - m * m;
        nrm[tid] = (float)m; nrm[35 + tid] = (float)rsqrt(v + (double)EPSB);
    }
    __syncthreads();
    int id = blockIdx.x * 256 + tid;
    float z[35];
#pragma unroll
    for (int j = 0; j < 35; j++) z[j] = 0.f;
#pragma unroll
    for (int k = 0; k < 35; k++) {
        float zk = Zin[(size_t)k * MROWS + id];            // coalesced
        float dk = fmaxf((zk - nrm[k]) * nrm[35 + k], 0.f); // fused normalize
        const float* wr = Wg + k * 35;
#pragma unroll
        for (int j = 0; j < 35; j++) z[j] = fmaf(dk, wr[j], z[j]);
    }
    int wv = tid >> 6;
#pragma unroll
    for (int j = 0; j < 35; j++) {
        float s = z[j], q = z[j] * z[j];
#pragma unroll
        for (int off = 32; off > 0; off >>= 1) { s += __shfl_down(s, off); q += __shfl_down(q, off); }
        if ((tid & 63) == 0) { redm[wv * 70 + j] = (double)s; redm[wv * 70 + 35 + j] = (double)q; }
    }
    __syncthreads();
    if (tid < 70) {
        double t = redm[tid] + redm[70 + tid] + redm[140 + tid] + redm[210 + tid];
        pout[(size_t)blockIdx.x * 70 + tid] = t;
    }
#pragma unroll
    for (int j = 0; j < 35; j++) Zout[(size_t)j * MROWS + id] = z[j];
}

__global__ __launch_bounds__(256)
void k_merge_out(const float* __restrict__ Zin, const float* __restrict__ Wout,
                 const float* __restrict__ bout, const double* __restrict__ pin,
                 const int* __restrict__ cand_batch, float* __restrict__ out,
                 int N, int ostride) {
    __shared__ float nrm[70];
    __shared__ double sred[70];
    __shared__ int cb[128];
    int tid = threadIdx.x;
    if (tid < 70) {
        double a0 = 0.0, a1 = 0.0, a2 = 0.0, a3 = 0.0;
#pragma unroll
        for (int b = 0; b < 64; b += 4) {
            a0 += pin[(size_t)b * 70 + tid];
            a1 += pin[(size_t)(b + 1) * 70 + tid];
            a2 += pin[(size_t)(b + 2) * 70 + tid];
            a3 += pin[(size_t)(b + 3) * 70 + tid];
        }
        sred[tid] = (a0 + a1) + (a2 + a3);
    }
    if (tid >= 128 && tid < 256) cb[tid - 128] = cand_batch[tid - 128];
    __syncthreads();
    if (tid < 35) {
        double m = sred[tid] * (1.0 / 16384.0);
        double v = sred[35 + tid] * (1.0 / 16384.0) - m * m;
        nrm[tid] = (float)m; nrm[35 + tid] = (float)rsqrt(v + (double)EPSB);
    }
    __syncthreads();
    int id = blockIdx.x * 256 + tid;
    int a = id >> 7, b = id & 127;
    float s = bout[0];
#pragma unroll
    for (int k = 0; k < 35; k++) {
        float zk = Zin[(size_t)k * MROWS + id];            // coalesced
        s = fmaf(fmaxf((zk - nrm[k]) * nrm[35 + k], 0.f), Wout[k], s);
    }
    float v = 1.f / (1.f + __expf(-s));
    if (cb[a] != cb[b]) v = 0.f;
    out[(size_t)a * ostride + N + b] = v;
}

// =============================== launcher =================================
extern "C" void kernel_launch(void* const* d_in, const int* in_sizes, int n_in,
                              void* d_out, int out_size, void* d_ws, size_t ws_size,
                              hipStream_t stream) {
    const float* of     = (const float*)d_in[0];
    const float* coords = (const float*)d_in[1];
    const float* heat   = (const float*)d_in[2];
    const int*   bidx   = (const int*)d_in[3];
    const float* Wm     = (const float*)d_in[4];
    const float* Wm_out = (const float*)d_in[5];
    const float* bm_out = (const float*)d_in[6];
    const float* Wk     = (const float*)d_in[7];
    const float* Wk_out = (const float*)d_in[8];
    const float* bk_out = (const float*)d_in[9];
    const float* Wg     = (const float*)d_in[10];
    const float* Wg_out = (const float*)d_in[11];
    const float* bg_out = (const float*)d_in[12];
    const float* Wwg    = (const float*)d_in[13];
    const float* bwg    = (const float*)d_in[14];
    float* out = (float*)d_out;
    float* ws  = (float*)d_ws;

    int N = in_sizes[0] / 32;          // 100000
    int ostride = N + 128;             // 100128

    float*  maskf = ws + OFF_MASKF;
    float*  kernf = ws + OFF_KERNF;
    float*  Vt    = ws + OFF_VT;
    float*  featw = ws + OFF_FEATW;
    int*    topk  = (int*)(ws + OFF_INT);
    int*    cand_batch = topk + 128;

    // tower BN partials ping-pong in mz1 region (dead before merge runs):
    double* TPA = (double*)(ws + OFF_MZ1);
    double* TPB = (double*)(ws + OFF_MZ1 + 131072);
    // merge BN partials in kernf region (dead after k_prep):
    double* P1 = (double*)(ws + OFF_KERNF);
    double* P2 = (double*)(ws + OFF_KERNF + 16384);
    double* P3 = (double*)(ws + OFF_KERNF + 32768);
    // merge Z ping-pong in WORKSPACE (573440 floats each; no d_out aliasing)
    float* Za = ws + OFF_MZ1;   // tower partials dead by merge time
    float* Zb = ws + OFF_MZ2;

    // tower ping-pong buffers live inside d_out (dead after towers)
    float* bufAm = out;
    float* bufBm = out + (size_t)N * 32;
    float* bufAk = out + (size_t)N * 64;
    float* bufBk = out + (size_t)N * 96;

    dim3 tg2((N + 255) / 256, 2);

    k_nms<<<4, 1024, 0, stream>>>(heat, coords, bidx, N, topk);
    k_tower2<32><<<tg2, 256, 0, stream>>>(of,    of,    Wm,        Wk,        nullptr, nullptr, bufAm, bufAk, nullptr, TPA,     N);
    k_tower2<32><<<tg2, 256, 0, stream>>>(bufAm, bufAk, Wm + 1024, Wk + 1024, nullptr, nullptr, bufBm, bufBk, TPA,     TPB,     N);
    k_tower2<32><<<tg2, 256, 0, stream>>>(bufBm, bufBk, Wm + 2048, Wk + 2048, nullptr, nullptr, bufAm, bufAk, TPB,     TPA,     N);
    k_tower2<16><<<tg2, 256, 0, stream>>>(bufAm, bufAk, Wm_out,    Wk_out,    bm_out,  bk_out,  maskf, kernf, TPA,     nullptr, N);

    k_prep<<<128, 384, 0, stream>>>(topk, coords, bidx, maskf, kernf, Wwg, bwg,
                                    Vt, featw, cand_batch);

    k_merge1<<<64, 256, 0, stream>>>(featw, Wg, Za, P1);
    k_merge_mid<<<64, 256, 0, stream>>>(Za, Wg + 1225, Zb, P1, P2);
    k_merge_mid<<<64, 256, 0, stream>>>(Zb, Wg + 2450, Za, P2, P3);
    k_merge_out<<<64, 256, 0, stream>>>(Za, Wg_out, bg_out, P3, cand_batch,
                                        out, N, ostride);

    k_mask<<<dim3((N + 255) / 256, 8), 256, 0, stream>>>(maskf, coords, Vt, out, N, ostride);
}